// Round 1
// baseline (190.063 us; speedup 1.0000x reference)
//
#include <hip/hip_runtime.h>
#include <hip/hip_bf16.h>
#include <math.h>
#include <float.h>

// Problem constants (x: [8192,128] f32, n_images=2)
static constexpr int NN    = 8192;
static constexpr int DD    = 128;
static constexpr int PP    = 4096;              // persons
static constexpr int TILE  = 128;
static constexpr int TT    = NN / TILE;         // 64 tiles per dim
static constexpr int NBLK  = TT * (TT + 1) / 2; // 2080 upper-tri tile pairs
static constexpr int NC    = NBLK * 2;          // 2 candidates per tile block

struct Cand { float v; unsigned idx; };

using short8 = __attribute__((ext_vector_type(8))) short;
using f32x4  = __attribute__((ext_vector_type(4))) float;

__device__ __forceinline__ unsigned pk2(float lo, float hi) {
    unsigned a = (unsigned)__builtin_bit_cast(unsigned short, __float2bfloat16(lo));
    unsigned b = (unsigned)__builtin_bit_cast(unsigned short, __float2bfloat16(hi));
    return a | (b << 16);
}

__device__ __forceinline__ void push1(float& v1, unsigned& i1, float& v2, unsigned& i2,
                                      float w, unsigned j) {
    if (w > v1) { v2 = v1; i2 = i1; v1 = w; i1 = j; }
    else if (w > v2) { v2 = w; i2 = j; }
}

__device__ __forceinline__ void merge2(float& v1, unsigned& i1, float& v2, unsigned& i2,
                                       float w1, unsigned j1, float w2, unsigned j2) {
    if (w1 > v1) {
        float nv2; unsigned ni2;
        if (v1 >= w2) { nv2 = v1; ni2 = i1; } else { nv2 = w2; ni2 = j2; }
        v1 = w1; i1 = j1; v2 = nv2; i2 = ni2;
    } else if (w1 > v2) {
        v2 = w1; i2 = j1;
    }
}

// ---- kernel 0: x -> bf16 copy (once) + sim_self in double ----
__global__ __launch_bounds__(256) void k_prep(const float* __restrict__ x,
                                              unsigned short* __restrict__ xb,
                                              double* __restrict__ ss) {
    const int tid = threadIdx.x;
    if (blockIdx.x < 256) {
        // 65536 chunks x 16 floats -> 16 bf16
        int chunk = blockIdx.x * 256 + tid;
        const float4* s = (const float4*)(x + (size_t)chunk * 16);
        float4 f0 = s[0], f1 = s[1], f2 = s[2], f3 = s[3];
        uint4 o0 = {pk2(f0.x, f0.y), pk2(f0.z, f0.w), pk2(f1.x, f1.y), pk2(f1.z, f1.w)};
        uint4 o1 = {pk2(f2.x, f2.y), pk2(f2.z, f2.w), pk2(f3.x, f3.y), pk2(f3.z, f3.w)};
        uint4* d = (uint4*)(xb + (size_t)chunk * 16);
        d[0] = o0; d[1] = o1;
    } else {
        // 64 blocks: sim_self[p] = dot(x[p], x[p+1]) in double, wave per person
        int b = blockIdx.x - 256;          // 0..63
        const int wv = tid >> 6, lane = tid & 63;
        #pragma unroll 4
        for (int u = 0; u < 16; ++u) {
            int p = b * 64 + wv * 16 + u;  // 0..4095
            const float* a  = x + (size_t)p * DD;
            const float* bb = a + DD;
            double s = (double)a[lane] * (double)bb[lane]
                     + (double)a[lane + 64] * (double)bb[lane + 64];
            #pragma unroll
            for (int off = 32; off >= 1; off >>= 1) s += __shfl_down(s, off);
            if (lane == 0) ss[p] = s;
        }
    }
}

// ---- kernel 1: MFMA top-2 over upper triangle of G = xb xb^T.
// K=128 is tiny: no LDS, no barriers. Each wave owns a 64x64 output tile and
// loads its A/B MFMA fragments straight from global (xb is 2MB -> L2-resident).
// 32 independent 16B loads per lane = full MLP; latency hidden in-wave + TLP. ----
__global__ __launch_bounds__(256) void k_top2(const unsigned short* __restrict__ xb,
                                              Cand* __restrict__ cands) {
    __shared__ float sv1[4], sv2[4];
    __shared__ unsigned si1[4], si2[4];

    const int tid  = threadIdx.x;
    const int wv   = tid >> 6;      // wave 0..3
    const int lane = tid & 63;

    // decode linear block id -> (ti, tj), ti <= tj
    int rem = blockIdx.x;
    int ti = 0;
    while (rem >= TT - ti) { rem -= (TT - ti); ++ti; }
    const int tj = ti + rem;

    const int wm   = wv >> 1;       // wave row 0..1
    const int wn   = wv & 1;        // wave col 0..1
    const int quad = lane >> 4;     // 0..3
    const int r16  = lane & 15;     // 0..15

    // MFMA 16x16x32 bf16 fragment layout (verified in prior rounds):
    // A: lane holds row (lane&15), k-elems (lane>>4)*8 .. +7 of each K=32 chunk.
    // B (Gram => symmetric): same pattern on xb row jbase + (lane&15).
    const unsigned short* arow = xb + (size_t)(ti * TILE + wm * 64 + r16) * DD + quad * 8;
    const unsigned short* brow = xb + (size_t)(tj * TILE + wn * 64 + r16) * DD + quad * 8;

    f32x4 acc[4][4];
    #pragma unroll
    for (int mi = 0; mi < 4; ++mi)
        #pragma unroll
        for (int nj = 0; nj < 4; ++nj)
            acc[mi][nj] = (f32x4){0.f, 0.f, 0.f, 0.f};

    #pragma unroll
    for (int kc = 0; kc < 4; ++kc) {           // 4 chunks of K=32
        short8 af[4], bq[4];
        #pragma unroll
        for (int mi = 0; mi < 4; ++mi) {
            af[mi] = *(const short8*)(arow + mi * (16 * DD) + kc * 32);
            bq[mi] = *(const short8*)(brow + mi * (16 * DD) + kc * 32);
        }
        #pragma unroll
        for (int mi = 0; mi < 4; ++mi)
            #pragma unroll
            for (int nj = 0; nj < 4; ++nj)
                acc[mi][nj] = __builtin_amdgcn_mfma_f32_16x16x32_bf16(
                    af[mi], bq[nj], acc[mi][nj], 0, 0, 0);
    }

    // ---- epilogue: per-lane top-2 over valid (i<j) ----
    // C/D layout: col = lane&15, row = (lane>>4)*4 + reg
    const int ibase = ti * TILE + wm * 64;
    const int jbase = tj * TILE + wn * 64;
    float v1 = -INFINITY, v2 = -INFINITY;
    unsigned i1 = 0, i2 = 0;
    #pragma unroll
    for (int mi = 0; mi < 4; ++mi) {
        #pragma unroll
        for (int nj = 0; nj < 4; ++nj) {
            int gj = jbase + nj * 16 + r16;
            #pragma unroll
            for (int reg = 0; reg < 4; ++reg) {
                int gi = ibase + mi * 16 + quad * 4 + reg;
                if (gi < gj) {
                    unsigned idx = (unsigned)(gi * NN + gj);
                    push1(v1, i1, v2, i2, acc[mi][nj][reg], idx);
                }
            }
        }
    }

    #pragma unroll
    for (int off = 32; off >= 1; off >>= 1) {
        float    w1 = __shfl_down(v1, off);
        unsigned j1 = (unsigned)__shfl_down((int)i1, off);
        float    w2 = __shfl_down(v2, off);
        unsigned j2 = (unsigned)__shfl_down((int)i2, off);
        merge2(v1, i1, v2, i2, w1, j1, w2, j2);
    }
    if (lane == 0) { sv1[wv] = v1; si1[wv] = i1; sv2[wv] = v2; si2[wv] = i2; }
    __syncthreads();
    if (tid == 0) {
        for (int w = 1; w < 4; ++w)
            merge2(v1, i1, v2, i2, sv1[w], si1[w], sv2[w], si2[w]);
        cands[blockIdx.x * 2]     = {v1, i1};
        cands[blockIdx.x * 2 + 1] = {v2, i2};
    }
}

// ---- kernel 2: approx top-2 -> exact recheck (double) -> final mean ----
// Widened to 1024 threads: candidate scans drop from 17 to 5 strided iters,
// person-mean loop from 16 to 4.
__global__ __launch_bounds__(1024) void k_final(const float* __restrict__ x,
                                                const double* __restrict__ ss,
                                                const Cand* __restrict__ cands,
                                                float* __restrict__ out) {
    __shared__ float redv[32];          // 16 waves x 2
    __shared__ float s_thresh;
    __shared__ int cnt;
    __shared__ unsigned qidx[128];
    __shared__ double qex[128];
    __shared__ double sd1, sd2;
    __shared__ unsigned stopi;
    __shared__ double sacc[1024];

    const int tid  = threadIdx.x;
    const int wv   = tid >> 6;          // 0..15
    const int lane = tid & 63;
    if (tid == 0) cnt = 0;

    // Phase A: approx global top-2 VALUES
    float v1 = -INFINITY, v2 = -INFINITY;
    for (int e = tid; e < NC; e += 1024) {
        float v = cands[e].v;
        if (v > v1) { v2 = v1; v1 = v; }
        else if (v > v2) v2 = v;
    }
    #pragma unroll
    for (int off = 32; off >= 1; off >>= 1) {
        float w1 = __shfl_down(v1, off);
        float w2 = __shfl_down(v2, off);
        if (w1 > v1) { v2 = (v1 >= w2) ? v1 : w2; v1 = w1; }
        else if (w1 > v2) v2 = w1;
    }
    if (lane == 0) { redv[wv * 2] = v1; redv[wv * 2 + 1] = v2; }
    __syncthreads();
    if (tid == 0) {
        float a1 = -INFINITY, a2 = -INFINITY;
        for (int e = 0; e < 32; ++e) {
            float v = redv[e];
            if (v > a1) { a2 = a1; a1 = v; }
            else if (v > a2) a2 = v;
        }
        s_thresh = a2 - 1.0f;   // margin >> bf16 dot-product error bound (~0.1)
    }
    __syncthreads();
    const float thresh = s_thresh;

    // Phase B: gather all candidates within margin of approx top-2
    for (int e = tid; e < NC; e += 1024) {
        if (cands[e].v >= thresh) {
            int k = atomicAdd(&cnt, 1);
            if (k < 128) qidx[k] = cands[e].idx;
        }
    }
    __syncthreads();
    const int n = cnt < 128 ? cnt : 128;

    // Phase C: exact double dot for each qualifying candidate (one wave each)
    for (int c = wv; c < n; c += 16) {
        unsigned idx = qidx[c];
        unsigned gi = idx >> 13;       // / 8192
        unsigned gj = idx & 8191;
        const float* pa = x + (size_t)gi * DD;
        const float* pb = x + (size_t)gj * DD;
        double s = (double)pa[lane] * (double)pb[lane]
                 + (double)pa[lane + 64] * (double)pb[lane + 64];
        #pragma unroll
        for (int off = 32; off >= 1; off >>= 1) s += __shfl_down(s, off);
        if (lane == 0) qex[c] = s;
    }
    __syncthreads();

    // Phase D: exact top-2 over rechecked candidates
    if (tid == 0) {
        double d1 = -DBL_MAX, d2 = -DBL_MAX;
        unsigned bi = 0;
        for (int c = 0; c < n; ++c) {
            double v = qex[c];
            if (v > d1) { d2 = d1; d1 = v; bi = qidx[c]; }
            else if (v > d2) d2 = v;
        }
        sd1 = d1; sd2 = d2; stopi = bi;
    }
    __syncthreads();

    const double top1 = sd1, top2 = sd2;
    const unsigned topi = stopi;

    // Phase E: mean(sim_oth / sim_self)
    double acc = 0.0;
    for (int p = tid; p < PP; p += 1024) {
        unsigned selfidx = (unsigned)(p * NN + p + 1);
        double so = (topi == selfidx) ? top2 : top1;
        acc += so / ss[p];
    }
    sacc[tid] = acc;
    __syncthreads();
    for (int s = 512; s >= 1; s >>= 1) {
        if (tid < s) sacc[tid] += sacc[tid + s];
        __syncthreads();
    }
    if (tid == 0) out[0] = (float)(sacc[0] / (double)PP);
}

extern "C" void kernel_launch(void* const* d_in, const int* in_sizes, int n_in,
                              void* d_out, int out_size, void* d_ws, size_t ws_size,
                              hipStream_t stream) {
    (void)in_sizes; (void)n_in; (void)out_size; (void)ws_size;
    const float* x = (const float*)d_in[0];
    float* out = (float*)d_out;

    double* ss  = (double*)d_ws;                                  // 32 KB
    Cand* cands = (Cand*)((char*)d_ws + PP * sizeof(double));     // ~33 KB
    unsigned short* xb = (unsigned short*)((char*)d_ws + 131072); // 2 MB bf16 copy

    k_prep<<<320, 256, 0, stream>>>(x, xb, ss);
    k_top2<<<NBLK, 256, 0, stream>>>(xb, cands);
    k_final<<<1, 1024, 0, stream>>>(x, ss, cands, out);
}